// Round 7
// baseline (3513.809 us; speedup 1.0000x reference)
//
#include <hip/hip_runtime.h>
#include <math.h>

typedef __attribute__((ext_vector_type(8))) short v8s;
typedef __attribute__((ext_vector_type(4))) float v4f;

#define AP 136              // padded LDS row stride (shorts); 272 B rows keep 16B align
#define OFF_W3 0
#define OFF_WI 524288
#define OFF_W1 528384
#define OFF_W2 544768
#define OFF_WR 561152
#define LO     565248       // lo-residual region offset (shorts)
#define WF_TOTAL2 1130496   // hi+lo regions (shorts, 2.26 MB)
#define KBUF_BYTE 2260992   // float kbuf[16 bg][2 par][2048]  (256 KB)
#define FLG_BYTE  2523136   // uint flags[16 bg][16 tr] @ 128 B spacing (32 KB)
#define FLG_SIZE  32768

static __device__ __forceinline__ float bf2f(unsigned short s){
    union { unsigned u; float f; } v; v.u = ((unsigned)s) << 16; return v.f;
}
static __device__ __forceinline__ unsigned short f2bf(float f){
    union { float ff; unsigned u; } v; v.ff = f;
    return (unsigned short)((v.u + 0x7FFFu + ((v.u >> 16) & 1u)) >> 16);
}
// triple split: v = h + m + l + eps, |eps| <= 2^-27 |v|
static __device__ __forceinline__ void split3(float v, unsigned short& h,
                                              unsigned short& m, unsigned short& l){
    h = f2bf(v);  float r1 = v - bf2f(h);
    m = f2bf(r1); float r2 = r1 - bf2f(m);
    l = f2bf(r2);
}
static __device__ __forceinline__ float softplus_f(float x){
    float t = __builtin_amdgcn_exp2f(x * 1.44269504088896341f);
    float r = 0.69314718055994531f * __builtin_amdgcn_logf(1.0f + t);
    return (x > 20.0f) ? x : r;
}
static __device__ __forceinline__ float tanh_f(float x){
    float xc = fminf(fmaxf(x, -9.0f), 9.0f);
    float t = __builtin_amdgcn_exp2f(xc * 2.8853900817779268f); // e^{2x}
    float d = t + 1.0f;
    float r = __builtin_amdgcn_rcpf(d);
    r = r * (2.0f - d * r);                                     // NR refine
    return (t - 1.0f) * r;
}

#define MFMA(acc, a, b) acc = __builtin_amdgcn_mfma_f32_16x16x32_bf16(a, b, acc, 0, 0, 0)

// ---------------------------------------------------------------------------
// fp32 weight -> bf16 hi + bf16 lo-residual MFMA B-fragment layout:
// frag elem = W[kt*32 + (lane>>4)*8 + j][nt*16 + (lane&15)]
// ---------------------------------------------------------------------------
__global__ void prep_kernel(const float* __restrict__ W,
                            unsigned short* __restrict__ dst,
                            int KT, int N, int total, int base, int wlimit){
    int tid = blockIdx.x * 256 + threadIdx.x;
    if (tid >= total) return;
    int j  = tid & 7;
    int l  = (tid >> 3) & 63;
    int t2 = tid >> 9;
    int kt = t2 % KT;
    int nt = t2 / KT;
    int row = kt * 32 + (l >> 4) * 8 + j;
    int col = nt * 16 + (l & 15);
    float w = W[(size_t)row * N + col];
    unsigned short h = f2bf(w);
    if (base + tid < wlimit)      dst[base + tid]      = h;
    if (base + LO + tid < wlimit) dst[base + LO + tid] = f2bf(w - bf2f(h));
}

// B-fragment pair (two 16-col tiles), hi+lo: 16 v8s = 64 VGPRs
struct BFrag { v8s h[2][4]; v8s l[2][4]; };

static __device__ __forceinline__ BFrag load_bfrag(const unsigned short* __restrict__ wf,
                                                   int wbase, int p, int lane){
    BFrag f;
#pragma unroll
    for (int i = 0; i < 2; ++i){
        int nt = 2 * p + i;
#pragma unroll
        for (int kt = 0; kt < 4; ++kt){
            int o = wbase + ((nt * 4 + kt) * 64 + lane) * 8;
            f.h[i][kt] = *(const v8s*)&wf[o];
            f.l[i][kt] = *(const v8s*)&wf[o + LO];
        }
    }
    return f;
}

// 40-MFMA pair compute, exact r6 ordering (bit-identical accumulation)
static __device__ __forceinline__ void mfma_pair(v4f& acc0, v4f& acc1,
    const v8s* ah, const v8s* am, const v8s* al, const BFrag& f){
#pragma unroll
    for (int kt = 0; kt < 4; ++kt){
        MFMA(acc0, ah[kt], f.h[0][kt]); MFMA(acc0, am[kt], f.h[0][kt]); MFMA(acc0, al[kt], f.h[0][kt]);
        MFMA(acc0, ah[kt], f.l[0][kt]); MFMA(acc0, am[kt], f.l[0][kt]);
        MFMA(acc1, ah[kt], f.h[1][kt]); MFMA(acc1, am[kt], f.h[1][kt]); MFMA(acc1, al[kt], f.h[1][kt]);
        MFMA(acc1, ah[kt], f.l[1][kt]); MFMA(acc1, am[kt], f.l[1][kt]);
    }
}

// all-wave flag poll: wave proceeds when all 16 producer flags >= tgt
static __device__ __forceinline__ void poll_flags(const unsigned int* __restrict__ teamflg,
                                                  unsigned tgt, int lane){
    unsigned it = 0;
    for (;;){
        unsigned fv = tgt;
        if (lane < 16)
            fv = __hip_atomic_load(&teamflg[lane * 32], __ATOMIC_RELAXED,
                                   __HIP_MEMORY_SCOPE_AGENT);
        if (__all((int)(fv >= tgt))) break;
        if (++it >= (1u << 22)) break;   // terminate-don't-hang safety
        __builtin_amdgcn_s_sleep(1);
    }
}

// ---------------------------------------------------------------------------
// gemm5 (5-MFMA split GEMM, global B-frags) -- used for Wi prologue / Wr epilogue
// ---------------------------------------------------------------------------
template<int KT, int MODE>
static __device__ __forceinline__ void gemm5(
    const unsigned short* __restrict__ wf, int wbase, int npairs,
    const unsigned short* Ah, const unsigned short* Am, const unsigned short* Al,
    float* zx,
    const float* __restrict__ bias_g,
    const float* __restrict__ xlast, float* __restrict__ outg, int bg)
{
    const int tid  = threadIdx.x;
    const int lane = tid & 63;
    const int wid  = tid >> 6;
    const int l15  = lane & 15;
    const int q    = lane >> 4;

    v8s ah[KT], am[KT], al[KT];
#pragma unroll
    for (int kt = 0; kt < KT; ++kt){
        ah[kt] = *(const v8s*)&Ah[l15 * AP + kt * 32 + q * 8];
        am[kt] = *(const v8s*)&Am[l15 * AP + kt * 32 + q * 8];
        al[kt] = *(const v8s*)&Al[l15 * AP + kt * 32 + q * 8];
    }

    for (int p = wid; p < npairs; p += 4){
        const int nt0 = 2 * p, nt1 = 2 * p + 1;
        v4f acc0 = {0.f, 0.f, 0.f, 0.f};
        v4f acc1 = {0.f, 0.f, 0.f, 0.f};
#pragma unroll
        for (int kt = 0; kt < KT; ++kt){
            int o0 = wbase + ((nt0 * KT + kt) * 64 + lane) * 8;
            int o1 = wbase + ((nt1 * KT + kt) * 64 + lane) * 8;
            v8s bh0 = *(const v8s*)&wf[o0];
            v8s bl0 = *(const v8s*)&wf[o0 + LO];
            v8s bh1 = *(const v8s*)&wf[o1];
            v8s bl1 = *(const v8s*)&wf[o1 + LO];
            MFMA(acc0, ah[kt], bh0); MFMA(acc0, am[kt], bh0); MFMA(acc0, al[kt], bh0);
            MFMA(acc0, ah[kt], bl0); MFMA(acc0, am[kt], bl0);
            MFMA(acc1, ah[kt], bh1); MFMA(acc1, am[kt], bh1); MFMA(acc1, al[kt], bh1);
            MFMA(acc1, ah[kt], bl1); MFMA(acc1, am[kt], bl1);
        }
        const int c0 = nt0 * 16 + l15, c1 = nt1 * 16 + l15;

        if (MODE == 0){
#pragma unroll
            for (int r = 0; r < 4; ++r){
                int b = q * 4 + r;
                zx[b * 128 + c0] = acc0[r] + bias_g[c0];
                zx[b * 128 + c1] = acc1[r] + bias_g[c1];
            }
        } else { // MODE 4
#pragma unroll
            for (int r = 0; r < 4; ++r){
                int b = q * 4 + r, gb = bg * 16 + b;
                outg[gb * 32 + c0] = acc0[r] + bias_g[c0] + xlast[gb * 32 + c0];
                outg[gb * 32 + c1] = acc1[r] + bias_g[c1] + xlast[gb * 32 + c1];
            }
        }
    }
}

// ---------------------------------------------------------------------------
// Dual-group pipelined persistent kernel: 128 blocks = 8 teams x 16 trs.
// Team t (XCD-local: blocks == t mod 8) serves batch-groups A=t and B=t+8,
// interleaved so each group's team-sync wait is hidden under the other
// group's compute. W1/W2/W3 B-fragments + biases register-cached.
// ---------------------------------------------------------------------------
__global__ __launch_bounds__(256) void cde_kernel(
    const float* __restrict__ coeffs,
    const float* __restrict__ x_last,
    const float* __restrict__ bi,
    const float* __restrict__ b1,
    const float* __restrict__ b2,
    const float* __restrict__ b3,
    const float* __restrict__ br,
    const unsigned short* __restrict__ wf,
    float* __restrict__ kbuf,
    unsigned int* __restrict__ flgs,
    float* __restrict__ outg)
{
    __shared__ unsigned short A0h[16*AP] __attribute__((aligned(16)));
    __shared__ unsigned short A0m[16*AP] __attribute__((aligned(16)));
    __shared__ unsigned short A0l[16*AP] __attribute__((aligned(16)));
    __shared__ unsigned short A1h[16*AP] __attribute__((aligned(16)));
    __shared__ unsigned short A1m[16*AP] __attribute__((aligned(16)));
    __shared__ unsigned short A1l[16*AP] __attribute__((aligned(16)));
    __shared__ unsigned short A2h[16*AP] __attribute__((aligned(16)));
    __shared__ unsigned short A2m[16*AP] __attribute__((aligned(16)));
    __shared__ unsigned short A2l[16*AP] __attribute__((aligned(16)));
    __shared__ float dval[512];
    __shared__ float zx[2048];

    const int tid  = threadIdx.x;
    const int lane = tid & 63;
    const int wid  = tid >> 6;
    const int l15  = lane & 15;
    const int q    = lane >> 4;
    const int bx   = blockIdx.x;
    const int team = bx & 7;          // team members share bx%8 -> same XCD
    const int tr   = bx >> 3;
    const int bgA  = team, bgB = team + 8;

    float*        kbA  = kbuf + bgA * 4096;     // [par][2048]
    float*        kbB  = kbuf + bgB * 4096;
    unsigned int* flgA = flgs + bgA * 512;      // 16 flags @ 128 B
    unsigned int* flgB = flgs + bgB * 512;
    unsigned int* myfA = flgA + tr * 32;
    unsigned int* myfB = flgB + tr * 32;

    for (int e = tid; e < 16*AP; e += 256){
        A0h[e]=0; A0m[e]=0; A0l[e]=0; A1h[e]=0; A1m[e]=0; A1l[e]=0;
        A2h[e]=0; A2m[e]=0; A2l[e]=0;
    }

    // register-cached weight fragments (shared by both groups)
    v8s w3h[2][2][4], w3l[2][2][4];   // [pi][tile][kt]
#pragma unroll
    for (int pi = 0; pi < 2; ++pi){
        int p = wid + 4 * pi;
#pragma unroll
        for (int i = 0; i < 2; ++i){
            int ntg = tr * 16 + 2 * p + i;
#pragma unroll
            for (int kt = 0; kt < 4; ++kt){
                int o = ((ntg * 4 + kt) * 64 + lane) * 8;   // OFF_W3 = 0
                w3h[pi][i][kt] = *(const v8s*)&wf[o];
                w3l[pi][i][kt] = *(const v8s*)&wf[o + LO];
            }
        }
    }
    BFrag w1f = load_bfrag(wf, OFF_W1, wid, lane);
    BFrag w2f = load_bfrag(wf, OFF_W2, wid, lane);

    // register-cached biases (per-lane constants)
    const int c0 = wid * 32 + l15, c1 = c0 + 16;
    const float b1v0 = b1[c0], b1v1 = b1[c1];
    const float b2v0 = b2[c0], b2v1 = b2[c1];
    float b3v[2][2];
#pragma unroll
    for (int pi = 0; pi < 2; ++pi){
        int cg0 = tr * 256 + (wid + 4 * pi) * 32 + l15;
        b3v[pi][0] = b3[cg0]; b3v[pi][1] = b3[cg0 + 16];
    }

    const int arow = tid >> 4;
    const int acol = (tid & 15) * 8;

    float zpA[8], kapA[8], k1A[8], k2A[8];
    float zpB[8], kapB[8], k1B[8], k2B[8];
#pragma unroll
    for (int i = 0; i < 8; ++i){ kapA[i]=0.f; k1A[i]=0.f; k2A[i]=0.f;
                                 kapB[i]=0.f; k1B[i]=0.f; k2B[i]=0.f; }

    // prologue: z0 = a0 @ Wi + bi for both groups
    auto init_z = [&](int bg, float (&zp)[8]){
        __syncthreads();
        for (int e = tid; e < 512; e += 256){
            int r = e >> 5, c = e & 31;
            float v = coeffs[((size_t)(bg * 16 + r) * 64) * 128 + c];
            unsigned short h, m, l; split3(v, h, m, l);
            A0h[r*AP+c] = h; A0m[r*AP+c] = m; A0l[r*AP+c] = l;
        }
        __syncthreads();
        gemm5<1, 0>(wf, OFF_WI, 4, A0h, A0m, A0l, zx, bi, nullptr, nullptr, bg);
        __syncthreads();
#pragma unroll
        for (int i = 0; i < 8; ++i) zp[i] = zx[tid*8 + i];
    };
    init_z(bgA, zpA);
    init_z(bgB, zpB);

    // per-stage compute for one group
    auto do_stage = [&](int s, int bg, float (&zp)[8], float (&kap)[8],
                        float* kb0, unsigned int* myflag){
        const int stp = s >> 2, sub = s & 3;
        int idx; float frac;
        if      (sub == 0){ idx = stp; frac = 0.f; }
        else if (sub == 1){ idx = stp; frac = 1.f / 3.f; }
        else if (sub == 2){ idx = stp; frac = 2.f / 3.f; }
        else { idx = (stp < 63) ? stp + 1 : 63; frac = (stp < 63) ? 0.f : 1.f; }

        for (int e = tid; e < 512; e += 256){
            int r = e >> 5, c = e & 31;
            size_t base = ((size_t)(bg * 16 + r) * 64 + idx) * 128;
            dval[e] = coeffs[base + 32 + c]
                    + (coeffs[base + 64 + c] + coeffs[base + 96 + c] * frac) * frac;
        }
        {   // stage A0 from private state
            v8s vh, vm, vl;
#pragma unroll
            for (int i = 0; i < 8; ++i){
                float v = (sub == 0) ? zp[i] : kap[i];
                unsigned short h, m, l; split3(v, h, m, l);
                vh[i] = (short)h; vm[i] = (short)m; vl[i] = (short)l;
            }
            *(v8s*)&A0h[arow*AP + acol] = vh;
            *(v8s*)&A0m[arow*AP + acol] = vm;
            *(v8s*)&A0l[arow*AP + acol] = vl;
        }
        __syncthreads();
        {   // W1 (cached frags) -> A1
            v8s ah[4], am[4], al[4];
#pragma unroll
            for (int kt = 0; kt < 4; ++kt){
                ah[kt] = *(const v8s*)&A0h[l15*AP + kt*32 + q*8];
                am[kt] = *(const v8s*)&A0m[l15*AP + kt*32 + q*8];
                al[kt] = *(const v8s*)&A0l[l15*AP + kt*32 + q*8];
            }
            v4f acc0 = {0.f,0.f,0.f,0.f}, acc1 = {0.f,0.f,0.f,0.f};
            mfma_pair(acc0, acc1, ah, am, al, w1f);
#pragma unroll
            for (int r = 0; r < 4; ++r){
                int b = q * 4 + r;
                float v0 = softplus_f(acc0[r] + b1v0);
                float v1 = softplus_f(acc1[r] + b1v1);
                unsigned short h, m, l;
                split3(v0, h, m, l); A1h[b*AP+c0]=h; A1m[b*AP+c0]=m; A1l[b*AP+c0]=l;
                split3(v1, h, m, l); A1h[b*AP+c1]=h; A1m[b*AP+c1]=m; A1l[b*AP+c1]=l;
            }
        }
        __syncthreads();
        {   // W2 (cached frags) -> A2
            v8s ah[4], am[4], al[4];
#pragma unroll
            for (int kt = 0; kt < 4; ++kt){
                ah[kt] = *(const v8s*)&A1h[l15*AP + kt*32 + q*8];
                am[kt] = *(const v8s*)&A1m[l15*AP + kt*32 + q*8];
                al[kt] = *(const v8s*)&A1l[l15*AP + kt*32 + q*8];
            }
            v4f acc0 = {0.f,0.f,0.f,0.f}, acc1 = {0.f,0.f,0.f,0.f};
            mfma_pair(acc0, acc1, ah, am, al, w2f);
#pragma unroll
            for (int r = 0; r < 4; ++r){
                int b = q * 4 + r;
                float v0 = softplus_f(acc0[r] + b2v0);
                float v1 = softplus_f(acc1[r] + b2v1);
                unsigned short h, m, l;
                split3(v0, h, m, l); A2h[b*AP+c0]=h; A2m[b*AP+c0]=m; A2l[b*AP+c0]=l;
                split3(v1, h, m, l); A2h[b*AP+c1]=h; A2m[b*AP+c1]=m; A2l[b*AP+c1]=l;
            }
        }
        __syncthreads();
        {   // W3 slice (cached frags) -> k slice -> kbuf
            float* kbw = kb0 + (s & 1) * 2048;
            v8s ah[4], am[4], al[4];
#pragma unroll
            for (int kt = 0; kt < 4; ++kt){
                ah[kt] = *(const v8s*)&A2h[l15*AP + kt*32 + q*8];
                am[kt] = *(const v8s*)&A2m[l15*AP + kt*32 + q*8];
                al[kt] = *(const v8s*)&A2l[l15*AP + kt*32 + q*8];
            }
            float dv0[4], dv1[4];
#pragma unroll
            for (int r = 0; r < 4; ++r){
                dv0[r] = dval[(q*4 + r) * 32 + l15];
                dv1[r] = dval[(q*4 + r) * 32 + 16 + l15];
            }
#pragma unroll
            for (int pi = 0; pi < 2; ++pi){
                int p = wid + 4 * pi;
                v4f acc0 = {0.f,0.f,0.f,0.f}, acc1 = {0.f,0.f,0.f,0.f};
#pragma unroll
                for (int kt = 0; kt < 4; ++kt){
                    MFMA(acc0, ah[kt], w3h[pi][0][kt]); MFMA(acc0, am[kt], w3h[pi][0][kt]);
                    MFMA(acc0, al[kt], w3h[pi][0][kt]);
                    MFMA(acc0, ah[kt], w3l[pi][0][kt]); MFMA(acc0, am[kt], w3l[pi][0][kt]);
                    MFMA(acc1, ah[kt], w3h[pi][1][kt]); MFMA(acc1, am[kt], w3h[pi][1][kt]);
                    MFMA(acc1, al[kt], w3h[pi][1][kt]);
                    MFMA(acc1, ah[kt], w3l[pi][1][kt]); MFMA(acc1, am[kt], w3l[pi][1][kt]);
                }
                float s4[4];
#pragma unroll
                for (int r = 0; r < 4; ++r){
                    float u0 = acc0[r] + b3v[pi][0];
                    float u1 = acc1[r] + b3v[pi][1];
                    s4[r] = tanh_f(u0) * dv0[r] + tanh_f(u1) * dv1[r];
                }
#pragma unroll
                for (int sm = 1; sm <= 8; sm <<= 1){
#pragma unroll
                    for (int r = 0; r < 4; ++r) s4[r] += __shfl_xor(s4[r], sm);
                }
                if (l15 == 0){
#pragma unroll
                    for (int r = 0; r < 4; ++r)
                        __hip_atomic_store(&kbw[(q*4 + r) * 128 + tr * 8 + p], s4[r],
                                           __ATOMIC_RELAXED, __HIP_MEMORY_SCOPE_AGENT);
                }
            }
        }
        __syncthreads();   // drains kbuf stores (vmcnt) for all waves
        if (tid == 0)
            __hip_atomic_store(myflag, (unsigned)(s + 1),
                               __ATOMIC_RELEASE, __HIP_MEMORY_SCOPE_AGENT);
    };

    auto do_update = [&](int s, float (&zp)[8], float (&kap)[8],
                         float (&k1p)[8], float (&k2p)[8],
                         float* kb0, const unsigned int* teamflg){
        poll_flags(teamflg, (unsigned)(s + 1), lane);
        const int sub = s & 3;
        const float* kbw = kb0 + (s & 1) * 2048;
        float kv[8];
#pragma unroll
        for (int i = 0; i < 8; ++i)
            kv[i] = __hip_atomic_load(&kbw[tid*8 + i], __ATOMIC_RELAXED,
                                      __HIP_MEMORY_SCOPE_AGENT);
#pragma unroll
        for (int i = 0; i < 8; ++i){
            float k = kv[i];
            if      (sub == 0){ k1p[i] = k; kap[i] = zp[i] + k * (1.f/3.f); }
            else if (sub == 1){ k2p[i] = k; kap[i] = zp[i] + (k - k1p[i] * (1.f/3.f)); }
            else if (sub == 2){ kap[i] = zp[i] + (k1p[i] - k2p[i] + k); }
            else { zp[i] = zp[i] + (6.f*k2p[i] - 2.f*k1p[i]
                                    + 3.f*(kap[i] - zp[i]) + k) * 0.125f; }
        }
    };

    // pipelined main loop: group X's team-wait hides under group Y's compute
    for (int s = 0; s < 256; ++s){
        if (s > 0) do_update(s - 1, zpA, kapA, k1A, k2A, kbA, flgA);
        do_stage(s, bgA, zpA, kapA, kbA, myfA);
        if (s > 0) do_update(s - 1, zpB, kapB, k1B, k2B, kbB, flgB);
        do_stage(s, bgB, zpB, kapB, kbB, myfB);
    }
    do_update(255, zpA, kapA, k1A, k2A, kbA, flgA);
    do_update(255, zpB, kapB, k1B, k2B, kbB, flgB);

    // epilogue: out = x_last + z @ Wr + br  (both groups)
    auto write_out = [&](int bg, float (&zp)[8]){
        v8s vh, vm, vl;
#pragma unroll
        for (int i = 0; i < 8; ++i){
            unsigned short h, m, l; split3(zp[i], h, m, l);
            vh[i] = (short)h; vm[i] = (short)m; vl[i] = (short)l;
        }
        *(v8s*)&A0h[arow*AP + acol] = vh;
        *(v8s*)&A0m[arow*AP + acol] = vm;
        *(v8s*)&A0l[arow*AP + acol] = vl;
        __syncthreads();
        gemm5<4, 4>(wf, OFF_WR, 1, A0h, A0m, A0l, nullptr, br, x_last, outg, bg);
        __syncthreads();
    };
    write_out(bgA, zpA);
    write_out(bgB, zpB);
}

extern "C" void kernel_launch(void* const* d_in, const int* in_sizes, int n_in,
                              void* d_out, int out_size, void* d_ws, size_t ws_size,
                              hipStream_t stream)
{
    const float* coeffs = (const float*)d_in[0];
    const float* x_last = (const float*)d_in[1];
    const float* Wi     = (const float*)d_in[2];
    const float* bi     = (const float*)d_in[3];
    const float* W1     = (const float*)d_in[4];
    const float* b1     = (const float*)d_in[5];
    const float* W2     = (const float*)d_in[6];
    const float* b2     = (const float*)d_in[7];
    const float* W3     = (const float*)d_in[8];
    const float* b3     = (const float*)d_in[9];
    const float* Wr     = (const float*)d_in[10];
    const float* br     = (const float*)d_in[11];
    unsigned short* wf  = (unsigned short*)d_ws;
    float*        kbuf  = (float*)((char*)d_ws + KBUF_BYTE);
    unsigned int* flgs  = (unsigned int*)((char*)d_ws + FLG_BYTE);

    size_t wcap = ws_size / 2;
    int wl = (wcap > (size_t)WF_TOTAL2) ? WF_TOTAL2 : (int)wcap;

    prep_kernel<<<(524288 + 255) / 256, 256, 0, stream>>>(W3, wf, 4, 4096, 524288, OFF_W3, wl);
    prep_kernel<<<(4096   + 255) / 256, 256, 0, stream>>>(Wi, wf, 1, 128,  4096,   OFF_WI, wl);
    prep_kernel<<<(16384  + 255) / 256, 256, 0, stream>>>(W1, wf, 4, 128,  16384,  OFF_W1, wl);
    prep_kernel<<<(16384  + 255) / 256, 256, 0, stream>>>(W2, wf, 4, 128,  16384,  OFF_W2, wl);
    prep_kernel<<<(4096   + 255) / 256, 256, 0, stream>>>(Wr, wf, 4, 32,   4096,   OFF_WR, wl);
    hipMemsetAsync((char*)d_ws + FLG_BYTE, 0, FLG_SIZE, stream);   // zero flags

    cde_kernel<<<128, 256, 0, stream>>>(coeffs, x_last, bi, b1, b2, b3, br, wf,
                                        kbuf, flgs, (float*)d_out);
}